// Round 2
// baseline (8404.316 us; speedup 1.0000x reference)
//
#include <hip/hip_runtime.h>

#define NND 50000
#define NED 1600000
#define EPSBN 1e-5f

// ---------------- degree ----------------
__global__ __launch_bounds__(256) void deg_kernel(const int* __restrict__ dst,
                                                  int* __restrict__ deg) {
    int i = blockIdx.x * 256 + threadIdx.x;
    if (i < NED) atomicAdd(&deg[dst[i]], 1);
}

__global__ __launch_bounds__(256) void deginv_kernel(const int* __restrict__ deg,
                                                     float* __restrict__ dinv) {
    int i = blockIdx.x * 256 + threadIdx.x;
    if (i < NND) dinv[i] = 1.0f / (float)(deg[i] > 1 ? deg[i] : 1);
}

// ---------------- scatter-add of gathered rows: 32 threads/edge, float4 ----------------
__global__ __launch_bounds__(256) void scatter_kernel(const float* __restrict__ x,
                                                      const int* __restrict__ src,
                                                      const int* __restrict__ dst,
                                                      float* __restrict__ agg) {
    int gid = blockIdx.x * 256 + threadIdx.x;
    int e = gid >> 5;
    if (e >= NED) return;
    int c4 = gid & 31;
    int s = src[e], d = dst[e];
    float4 v = ((const float4*)x)[(size_t)s * 32 + c4];
    float* base = agg + (size_t)d * 128 + c4 * 4;
    unsafeAtomicAdd(base + 0, v.x);
    unsafeAtomicAdd(base + 1, v.y);
    unsafeAtomicAdd(base + 2, v.z);
    unsafeAtomicAdd(base + 3, v.w);
}

// ---------------- pack [Wl | Wr] into K-major wcat[k][c] ----------------
template<int NOUT>
__global__ __launch_bounds__(256) void pack_w_kernel(const float* __restrict__ Wl,
                                                     const float* __restrict__ Wr,
                                                     float* __restrict__ wcat) {
    int t = blockIdx.x * 256 + threadIdx.x;
    if (t >= NOUT * 256) return;
    int k = t / NOUT, c = t % NOUT;
    wcat[t] = (k < 128) ? Wl[c * 128 + k] : Wr[c * 128 + (k - 128)];
}

// ---------------- fused dual GEMM: out = (agg*dinv)@Wl^T + xin@Wr^T + b ----------------
// A = [agg*dinv | xin]  (M x 256), W staged K-major. Optional BN stats epilogue.
// NOTE: out may alias xin (in-place layer): each block reads only its own 64 rows
// of xin, and all those reads complete before the epilogue stores. No __restrict__
// on xin/out for that reason.
template<int BN, bool DO_STATS>
__global__ __launch_bounds__(256) void gemm_kernel(const float* __restrict__ agg,
                                                   const float* __restrict__ dinv,
                                                   const float* xin,
                                                   const float* __restrict__ wcat,
                                                   const float* __restrict__ bias,
                                                   float* out,
                                                   float* __restrict__ stats) {
    constexpr int BM = 64, BK = 16, TM = 4, TN = BN / 16;
    constexpr int WSP = BN + 4;
    __shared__ float As[BK][BM + 4];
    __shared__ float Ws[BK][WSP];

    const int t = threadIdx.x;
    const int tx = t & 15, ty = t >> 4;
    const int row0 = blockIdx.x * BM;

    float acc[TM][TN];
#pragma unroll
    for (int r = 0; r < TM; ++r)
#pragma unroll
        for (int j = 0; j < TN; ++j) acc[r][j] = 0.f;

    const int ar = t >> 2, aq = t & 3;     // A staging: row ar, float4 index aq
    const int arow = row0 + ar;
    const bool avalid = arow < NND;
    const float dv = avalid ? dinv[arow] : 0.f;

    for (int kt = 0; kt < 16; ++kt) {
        const int k0 = kt * BK;
        // stage A (zero out-of-range rows so stats/acc stay clean)
        float4 av = make_float4(0.f, 0.f, 0.f, 0.f);
        if (avalid) {
            if (k0 < 128) {
                av = *(const float4*)(agg + (size_t)arow * 128 + k0 + aq * 4);
                av.x *= dv; av.y *= dv; av.z *= dv; av.w *= dv;
            } else {
                av = *(const float4*)(xin + (size_t)arow * 128 + (k0 - 128) + aq * 4);
            }
        }
        As[aq * 4 + 0][ar] = av.x;
        As[aq * 4 + 1][ar] = av.y;
        As[aq * 4 + 2][ar] = av.z;
        As[aq * 4 + 3][ar] = av.w;

        // stage W chunk (contiguous 16*BN floats)
        constexpr int WCNT = BK * BN / 4;
        const float4* wg = (const float4*)(wcat + k0 * BN);
#pragma unroll
        for (int i = 0; i < WCNT / 256; ++i) {
            int li = t + i * 256;
            float4 wv = wg[li];
            int kk = (li * 4) / BN, cc = (li * 4) % BN;
            Ws[kk][cc + 0] = wv.x;
            Ws[kk][cc + 1] = wv.y;
            Ws[kk][cc + 2] = wv.z;
            Ws[kk][cc + 3] = wv.w;
        }
        __syncthreads();
#pragma unroll
        for (int kk = 0; kk < BK; ++kk) {
            float a[TM], w[TN];
#pragma unroll
            for (int r = 0; r < TM; ++r) a[r] = As[kk][ty * TM + r];
#pragma unroll
            for (int j = 0; j < TN; ++j) w[j] = Ws[kk][tx * TN + j];
#pragma unroll
            for (int r = 0; r < TM; ++r)
#pragma unroll
                for (int j = 0; j < TN; ++j)
                    acc[r][j] = fmaf(a[r], w[j], acc[r][j]);
        }
        __syncthreads();
    }

    // epilogue: bias, store, BN partial stats
    float pb[TN];
#pragma unroll
    for (int j = 0; j < TN; ++j) pb[j] = bias[tx * TN + j];
    float psum[TN], psq[TN];
#pragma unroll
    for (int j = 0; j < TN; ++j) { psum[j] = 0.f; psq[j] = 0.f; }

#pragma unroll
    for (int r = 0; r < TM; ++r) {
        int row = row0 + ty * TM + r;
        if (row < NND) {
            float o[TN];
#pragma unroll
            for (int j = 0; j < TN; ++j) {
                o[j] = acc[r][j] + pb[j];
                if (DO_STATS) { psum[j] += o[j]; psq[j] += o[j] * o[j]; }
            }
#pragma unroll
            for (int j4 = 0; j4 < TN / 4; ++j4) {
                float4 v = make_float4(o[j4 * 4], o[j4 * 4 + 1], o[j4 * 4 + 2], o[j4 * 4 + 3]);
                *(float4*)(out + (size_t)row * BN + tx * TN + j4 * 4) = v;
            }
        }
    }

    if (DO_STATS) {
        // block-level column reduction in LDS (reuse Ws), then 1 atomic/col/block
#pragma unroll
        for (int j = 0; j < TN; ++j) Ws[ty][tx * TN + j] = psum[j];
        __syncthreads();
        if (t < BN) {
            float s = 0.f;
#pragma unroll
            for (int y = 0; y < 16; ++y) s += Ws[y][t];
            unsafeAtomicAdd(&stats[t], s);
        }
        __syncthreads();
#pragma unroll
        for (int j = 0; j < TN; ++j) Ws[ty][tx * TN + j] = psq[j];
        __syncthreads();
        if (t < BN) {
            float s = 0.f;
#pragma unroll
            for (int y = 0; y < 16; ++y) s += Ws[y][t];
            unsafeAtomicAdd(&stats[BN + t], s);
        }
    }
}

// ---------------- BN finalize: per-channel scale/shift ----------------
__global__ void bn_finalize_kernel(const float* __restrict__ stats,
                                   const float* __restrict__ gamma,
                                   const float* __restrict__ beta,
                                   float* __restrict__ ab) {
    int c = threadIdx.x;  // 128
    float mu = stats[c] * (1.0f / NND);
    float var = stats[128 + c] * (1.0f / NND) - mu * mu;
    float rs = rsqrtf(var + EPSBN);
    float a = gamma[c] * rs;
    ab[c] = a;
    ab[128 + c] = beta[c] - mu * a;
}

// ---------------- apply BN + ReLU in place ----------------
__global__ __launch_bounds__(256) void bn_relu_kernel(float* __restrict__ h,
                                                      const float* __restrict__ ab) {
    int i = blockIdx.x * 256 + threadIdx.x;
    if (i >= NND * 32) return;
    float4 v = ((float4*)h)[i];
    int c0 = (i & 31) * 4;
    v.x = fmaxf(v.x * ab[c0 + 0] + ab[128 + c0 + 0], 0.f);
    v.y = fmaxf(v.y * ab[c0 + 1] + ab[128 + c0 + 1], 0.f);
    v.z = fmaxf(v.z * ab[c0 + 2] + ab[128 + c0 + 2], 0.f);
    v.w = fmaxf(v.w * ab[c0 + 3] + ab[128 + c0 + 3], 0.f);
    ((float4*)h)[i] = v;
}

extern "C" void kernel_launch(void* const* d_in, const int* in_sizes, int n_in,
                              void* d_out, int out_size, void* d_ws, size_t ws_size,
                              hipStream_t stream) {
    const float* x   = (const float*)d_in[0];
    const int*   ei  = (const int*)d_in[1];
    const int* src = ei;
    const int* dst = ei + NED;
    const float* Wl0 = (const float*)d_in[2];
    const float* Wr0 = (const float*)d_in[3];
    const float* b0  = (const float*)d_in[4];
    const float* g0  = (const float*)d_in[5];
    const float* be0 = (const float*)d_in[6];
    const float* Wl1 = (const float*)d_in[7];
    const float* Wr1 = (const float*)d_in[8];
    const float* b1  = (const float*)d_in[9];
    const float* g1  = (const float*)d_in[10];
    const float* be1 = (const float*)d_in[11];
    const float* Wl2 = (const float*)d_in[12];
    const float* Wr2 = (const float*)d_in[13];
    const float* b2  = (const float*)d_in[14];
    float* out = (float*)d_out;

    // workspace layout (floats): agg | h | dinv | deg(int) | wcat | stats | ab
    // total ~51.5 MB
    float* ws = (float*)d_ws;
    const size_t NF = (size_t)NND * 128;
    float* agg   = ws;
    float* h     = agg + NF;
    float* dinv  = h + NF;
    int*   deg   = (int*)(dinv + NND);
    float* wcat  = (float*)(deg + NND);
    float* stats = wcat + 256 * 128;
    float* ab    = stats + 256;

    hipMemsetAsync(deg, 0, NND * sizeof(int), stream);
    deg_kernel<<<(NED + 255) / 256, 256, 0, stream>>>(dst, deg);
    deginv_kernel<<<(NND + 255) / 256, 256, 0, stream>>>(deg, dinv);

    const int SCB = (NED * 32) / 256;   // 200000 blocks
    const int GM  = (NND + 63) / 64;    // 782 blocks

    // ---- layer 0: x -> h ----
    hipMemsetAsync(agg, 0, NF * sizeof(float), stream);
    scatter_kernel<<<SCB, 256, 0, stream>>>(x, src, dst, agg);
    pack_w_kernel<128><<<128, 256, 0, stream>>>(Wl0, Wr0, wcat);
    hipMemsetAsync(stats, 0, 256 * sizeof(float), stream);
    gemm_kernel<128, true><<<GM, 256, 0, stream>>>(agg, dinv, x, wcat, b0, h, stats);
    bn_finalize_kernel<<<1, 128, 0, stream>>>(stats, g0, be0, ab);
    bn_relu_kernel<<<(NND * 32 + 255) / 256, 256, 0, stream>>>(h, ab);

    // ---- layer 1: h -> h (in-place GEMM) ----
    hipMemsetAsync(agg, 0, NF * sizeof(float), stream);
    scatter_kernel<<<SCB, 256, 0, stream>>>(h, src, dst, agg);
    pack_w_kernel<128><<<128, 256, 0, stream>>>(Wl1, Wr1, wcat);
    hipMemsetAsync(stats, 0, 256 * sizeof(float), stream);
    gemm_kernel<128, true><<<GM, 256, 0, stream>>>(agg, dinv, h, wcat, b1, h, stats);
    bn_finalize_kernel<<<1, 128, 0, stream>>>(stats, g1, be1, ab);
    bn_relu_kernel<<<(NND * 32 + 255) / 256, 256, 0, stream>>>(h, ab);

    // ---- layer 2: h -> d_out (no BN/ReLU) ----
    hipMemsetAsync(agg, 0, NF * sizeof(float), stream);
    scatter_kernel<<<SCB, 256, 0, stream>>>(h, src, dst, agg);
    pack_w_kernel<64><<<64, 256, 0, stream>>>(Wl2, Wr2, wcat);
    gemm_kernel<64, false><<<GM, 256, 0, stream>>>(agg, dinv, h, wcat, b2, out, nullptr);
}

// Round 3
// 810.176 us; speedup vs baseline: 10.3734x; 10.3734x over previous
//
#include <hip/hip_runtime.h>

#define NND 50000
#define NED 1600000
#define EPSBN 1e-5f
#define SCAN_B 256
#define NBLK ((NND + SCAN_B - 1) / SCAN_B)   // 196

// ---------------- degree histogram ----------------
__global__ __launch_bounds__(256) void deg_kernel(const int* __restrict__ dst,
                                                  int* __restrict__ deg) {
    int i = blockIdx.x * 256 + threadIdx.x;
    if (i < NED) atomicAdd(&deg[dst[i]], 1);
}

__global__ __launch_bounds__(256) void deginv_kernel(const int* __restrict__ deg,
                                                     float* __restrict__ dinv) {
    int i = blockIdx.x * 256 + threadIdx.x;
    if (i < NND) dinv[i] = 1.0f / (float)(deg[i] > 1 ? deg[i] : 1);
}

// ---------------- hierarchical exclusive scan: deg -> rowptr ----------------
__global__ __launch_bounds__(SCAN_B) void scan1_kernel(const int* __restrict__ deg,
                                                       int* __restrict__ rowptr,
                                                       int* __restrict__ bsum) {
    __shared__ int s[SCAN_B];
    int t = threadIdx.x;
    int i = blockIdx.x * SCAN_B + t;
    int v = (i < NND) ? deg[i] : 0;
    s[t] = v;
    __syncthreads();
#pragma unroll
    for (int o = 1; o < SCAN_B; o <<= 1) {
        int add = (t >= o) ? s[t - o] : 0;
        __syncthreads();
        s[t] += add;
        __syncthreads();
    }
    if (i < NND) rowptr[i] = s[t] - v;          // exclusive within block
    if (t == SCAN_B - 1) bsum[blockIdx.x] = s[t];
}

__global__ __launch_bounds__(SCAN_B) void scan2_kernel(int* __restrict__ bsum,
                                                       int* __restrict__ boff) {
    __shared__ int s[SCAN_B];
    int t = threadIdx.x;
    int v = (t < NBLK) ? bsum[t] : 0;
    s[t] = v;
    __syncthreads();
#pragma unroll
    for (int o = 1; o < SCAN_B; o <<= 1) {
        int add = (t >= o) ? s[t - o] : 0;
        __syncthreads();
        s[t] += add;
        __syncthreads();
    }
    if (t < NBLK) boff[t] = s[t] - v;           // exclusive block offsets
}

__global__ __launch_bounds__(SCAN_B) void scan3_kernel(int* __restrict__ rowptr,
                                                       const int* __restrict__ boff) {
    int i = blockIdx.x * SCAN_B + threadIdx.x;
    if (i < NND) rowptr[i] += boff[blockIdx.x];
    if (i == 0) rowptr[NND] = NED;
}

// ---------------- CSR fill: bucket src ids by dst ----------------
__global__ __launch_bounds__(256) void csr_fill_kernel(const int* __restrict__ src,
                                                       const int* __restrict__ dst,
                                                       const int* __restrict__ rowptr,
                                                       int* __restrict__ cnt,
                                                       int* __restrict__ csr_src) {
    int e = blockIdx.x * 256 + threadIdx.x;
    if (e >= NED) return;
    int d = dst[e];
    int pos = rowptr[d] + atomicAdd(&cnt[d], 1);
    csr_src[pos] = src[e];
}

// ---------------- gather-mean aggregation: 1 wave per node ----------------
// agg[i] = dinv[i] * sum_{j in N(i)} x[j]   (pre-scaled; GEMM no longer scales)
__global__ __launch_bounds__(256) void gather_kernel(const float* __restrict__ x,
                                                     const int* __restrict__ rowptr,
                                                     const int* __restrict__ csr_src,
                                                     const float* __restrict__ dinv,
                                                     float* __restrict__ agg) {
    int w = threadIdx.x >> 6;
    int node = blockIdx.x * 4 + w;
    if (node >= NND) return;
    int lane = threadIdx.x & 63;
    int half = lane >> 5;       // which neighbor of the pair
    int c4 = lane & 31;         // float4 index within the 128-ch row
    int beg = rowptr[node], end = rowptr[node + 1];

    float4 acc = make_float4(0.f, 0.f, 0.f, 0.f);
    for (int j = beg + half; j < end; j += 2) {
        int s = csr_src[j];
        float4 v = ((const float4*)x)[(size_t)s * 32 + c4];
        acc.x += v.x; acc.y += v.y; acc.z += v.z; acc.w += v.w;
    }
    // combine the two half-wave partials (lane l ^ 32 holds same channels)
    acc.x += __shfl_xor(acc.x, 32, 64);
    acc.y += __shfl_xor(acc.y, 32, 64);
    acc.z += __shfl_xor(acc.z, 32, 64);
    acc.w += __shfl_xor(acc.w, 32, 64);

    if (half == 0) {
        float dv = dinv[node];
        acc.x *= dv; acc.y *= dv; acc.z *= dv; acc.w *= dv;
        ((float4*)agg)[(size_t)node * 32 + c4] = acc;
    }
}

// ---------------- pack [Wl | Wr] into K-major wcat[k][c] ----------------
template<int NOUT>
__global__ __launch_bounds__(256) void pack_w_kernel(const float* __restrict__ Wl,
                                                     const float* __restrict__ Wr,
                                                     float* __restrict__ wcat) {
    int t = blockIdx.x * 256 + threadIdx.x;
    if (t >= NOUT * 256) return;
    int k = t / NOUT, c = t % NOUT;
    wcat[t] = (k < 128) ? Wl[c * 128 + k] : Wr[c * 128 + (k - 128)];
}

// ---------------- fused dual GEMM: out = agg@Wl^T + xin@Wr^T + b ----------------
// A = [agg | xin]  (M x 256), W staged K-major. Optional BN stats epilogue.
// out may alias xin (in-place layer): each block reads only its own 64 rows
// of xin; all reads complete before the epilogue stores.
template<int BN, bool DO_STATS>
__global__ __launch_bounds__(256) void gemm_kernel(const float* __restrict__ agg,
                                                   const float* xin,
                                                   const float* __restrict__ wcat,
                                                   const float* __restrict__ bias,
                                                   float* out,
                                                   float* __restrict__ stats) {
    constexpr int BM = 64, BK = 16, TM = 4, TN = BN / 16;
    constexpr int WSP = BN + 4;
    __shared__ float As[BK][BM + 4];
    __shared__ float Ws[BK][WSP];

    const int t = threadIdx.x;
    const int tx = t & 15, ty = t >> 4;
    const int row0 = blockIdx.x * BM;

    float acc[TM][TN];
#pragma unroll
    for (int r = 0; r < TM; ++r)
#pragma unroll
        for (int j = 0; j < TN; ++j) acc[r][j] = 0.f;

    const int ar = t >> 2, aq = t & 3;     // A staging: row ar, float4 index aq
    const int arow = row0 + ar;
    const bool avalid = arow < NND;

    for (int kt = 0; kt < 16; ++kt) {
        const int k0 = kt * BK;
        float4 av = make_float4(0.f, 0.f, 0.f, 0.f);
        if (avalid) {
            if (k0 < 128) {
                av = *(const float4*)(agg + (size_t)arow * 128 + k0 + aq * 4);
            } else {
                av = *(const float4*)(xin + (size_t)arow * 128 + (k0 - 128) + aq * 4);
            }
        }
        As[aq * 4 + 0][ar] = av.x;
        As[aq * 4 + 1][ar] = av.y;
        As[aq * 4 + 2][ar] = av.z;
        As[aq * 4 + 3][ar] = av.w;

        constexpr int WCNT = BK * BN / 4;
        const float4* wg = (const float4*)(wcat + k0 * BN);
#pragma unroll
        for (int i = 0; i < WCNT / 256; ++i) {
            int li = t + i * 256;
            float4 wv = wg[li];
            int kk = (li * 4) / BN, cc = (li * 4) % BN;
            Ws[kk][cc + 0] = wv.x;
            Ws[kk][cc + 1] = wv.y;
            Ws[kk][cc + 2] = wv.z;
            Ws[kk][cc + 3] = wv.w;
        }
        __syncthreads();
#pragma unroll
        for (int kk = 0; kk < BK; ++kk) {
            float a[TM], w[TN];
#pragma unroll
            for (int r = 0; r < TM; ++r) a[r] = As[kk][ty * TM + r];
#pragma unroll
            for (int j = 0; j < TN; ++j) w[j] = Ws[kk][tx * TN + j];
#pragma unroll
            for (int r = 0; r < TM; ++r)
#pragma unroll
                for (int j = 0; j < TN; ++j)
                    acc[r][j] = fmaf(a[r], w[j], acc[r][j]);
        }
        __syncthreads();
    }

    float pb[TN];
#pragma unroll
    for (int j = 0; j < TN; ++j) pb[j] = bias[tx * TN + j];
    float psum[TN], psq[TN];
#pragma unroll
    for (int j = 0; j < TN; ++j) { psum[j] = 0.f; psq[j] = 0.f; }

#pragma unroll
    for (int r = 0; r < TM; ++r) {
        int row = row0 + ty * TM + r;
        if (row < NND) {
            float o[TN];
#pragma unroll
            for (int j = 0; j < TN; ++j) {
                o[j] = acc[r][j] + pb[j];
                if (DO_STATS) { psum[j] += o[j]; psq[j] += o[j] * o[j]; }
            }
#pragma unroll
            for (int j4 = 0; j4 < TN / 4; ++j4) {
                float4 v = make_float4(o[j4 * 4], o[j4 * 4 + 1], o[j4 * 4 + 2], o[j4 * 4 + 3]);
                *(float4*)(out + (size_t)row * BN + tx * TN + j4 * 4) = v;
            }
        }
    }

    if (DO_STATS) {
#pragma unroll
        for (int j = 0; j < TN; ++j) Ws[ty][tx * TN + j] = psum[j];
        __syncthreads();
        if (t < BN) {
            float s = 0.f;
#pragma unroll
            for (int y = 0; y < 16; ++y) s += Ws[y][t];
            unsafeAtomicAdd(&stats[t], s);
        }
        __syncthreads();
#pragma unroll
        for (int j = 0; j < TN; ++j) Ws[ty][tx * TN + j] = psq[j];
        __syncthreads();
        if (t < BN) {
            float s = 0.f;
#pragma unroll
            for (int y = 0; y < 16; ++y) s += Ws[y][t];
            unsafeAtomicAdd(&stats[BN + t], s);
        }
    }
}

// ---------------- BN finalize ----------------
__global__ void bn_finalize_kernel(const float* __restrict__ stats,
                                   const float* __restrict__ gamma,
                                   const float* __restrict__ beta,
                                   float* __restrict__ ab) {
    int c = threadIdx.x;  // 128
    float mu = stats[c] * (1.0f / NND);
    float var = stats[128 + c] * (1.0f / NND) - mu * mu;
    float rs = rsqrtf(var + EPSBN);
    float a = gamma[c] * rs;
    ab[c] = a;
    ab[128 + c] = beta[c] - mu * a;
}

// ---------------- apply BN + ReLU in place ----------------
__global__ __launch_bounds__(256) void bn_relu_kernel(float* __restrict__ h,
                                                      const float* __restrict__ ab) {
    int i = blockIdx.x * 256 + threadIdx.x;
    if (i >= NND * 32) return;
    float4 v = ((float4*)h)[i];
    int c0 = (i & 31) * 4;
    v.x = fmaxf(v.x * ab[c0 + 0] + ab[128 + c0 + 0], 0.f);
    v.y = fmaxf(v.y * ab[c0 + 1] + ab[128 + c0 + 1], 0.f);
    v.z = fmaxf(v.z * ab[c0 + 2] + ab[128 + c0 + 2], 0.f);
    v.w = fmaxf(v.w * ab[c0 + 3] + ab[128 + c0 + 3], 0.f);
    ((float4*)h)[i] = v;
}

extern "C" void kernel_launch(void* const* d_in, const int* in_sizes, int n_in,
                              void* d_out, int out_size, void* d_ws, size_t ws_size,
                              hipStream_t stream) {
    const float* x   = (const float*)d_in[0];
    const int*   ei  = (const int*)d_in[1];
    const int* src = ei;
    const int* dst = ei + NED;
    const float* Wl0 = (const float*)d_in[2];
    const float* Wr0 = (const float*)d_in[3];
    const float* b0  = (const float*)d_in[4];
    const float* g0  = (const float*)d_in[5];
    const float* be0 = (const float*)d_in[6];
    const float* Wl1 = (const float*)d_in[7];
    const float* Wr1 = (const float*)d_in[8];
    const float* b1  = (const float*)d_in[9];
    const float* g1  = (const float*)d_in[10];
    const float* be1 = (const float*)d_in[11];
    const float* Wl2 = (const float*)d_in[12];
    const float* Wr2 = (const float*)d_in[13];
    const float* b2  = (const float*)d_in[14];
    float* out = (float*)d_out;

    // workspace (floats): agg | h | dinv | deg(int,reused as cnt) | rowptr | bsum | boff | wcat | stats | ab
    // ~51.9 MB total. csr_src (6.4 MB) lives in d_out (12.8 MB) — dead until layer-2 GEMM.
    float* ws = (float*)d_ws;
    const size_t NF = (size_t)NND * 128;
    float* agg    = ws;
    float* h      = agg + NF;
    float* dinv   = h + NF;
    int*   deg    = (int*)(dinv + NND);          // later reused as fill cursor
    int*   rowptr = deg + NND;                   // NND+1
    int*   bsum   = rowptr + NND + 1;            // NBLK
    int*   boff   = bsum + NBLK;                 // NBLK
    float* wcat   = (float*)(boff + NBLK);
    float* stats  = wcat + 256 * 128;
    float* ab     = stats + 256;
    int*   csr_src = (int*)d_out;                // 1.6M ints = 6.4 MB of the 12.8 MB output

    const int GB  = (NND + 3) / 4;      // gather blocks (4 nodes each)
    const int GM  = (NND + 63) / 64;    // gemm blocks

    // ---- CSR build (once; shared by all 3 layers) ----
    hipMemsetAsync(deg, 0, NND * sizeof(int), stream);
    deg_kernel<<<(NED + 255) / 256, 256, 0, stream>>>(dst, deg);
    deginv_kernel<<<(NND + 255) / 256, 256, 0, stream>>>(deg, dinv);
    scan1_kernel<<<NBLK, SCAN_B, 0, stream>>>(deg, rowptr, bsum);
    scan2_kernel<<<1, SCAN_B, 0, stream>>>(bsum, boff);
    scan3_kernel<<<NBLK, SCAN_B, 0, stream>>>(rowptr, boff);
    hipMemsetAsync(deg, 0, NND * sizeof(int), stream);   // reuse deg as cursor
    csr_fill_kernel<<<(NED + 255) / 256, 256, 0, stream>>>(src, dst, rowptr, deg, csr_src);

    // ---- layer 0: x -> h ----
    gather_kernel<<<GB, 256, 0, stream>>>(x, rowptr, csr_src, dinv, agg);
    pack_w_kernel<128><<<128, 256, 0, stream>>>(Wl0, Wr0, wcat);
    hipMemsetAsync(stats, 0, 256 * sizeof(float), stream);
    gemm_kernel<128, true><<<GM, 256, 0, stream>>>(agg, x, wcat, b0, h, stats);
    bn_finalize_kernel<<<1, 128, 0, stream>>>(stats, g0, be0, ab);
    bn_relu_kernel<<<(NND * 32 + 255) / 256, 256, 0, stream>>>(h, ab);

    // ---- layer 1: h -> h (in-place GEMM) ----
    gather_kernel<<<GB, 256, 0, stream>>>(h, rowptr, csr_src, dinv, agg);
    pack_w_kernel<128><<<128, 256, 0, stream>>>(Wl1, Wr1, wcat);
    hipMemsetAsync(stats, 0, 256 * sizeof(float), stream);
    gemm_kernel<128, true><<<GM, 256, 0, stream>>>(agg, h, wcat, b1, h, stats);
    bn_finalize_kernel<<<1, 128, 0, stream>>>(stats, g1, be1, ab);
    bn_relu_kernel<<<(NND * 32 + 255) / 256, 256, 0, stream>>>(h, ab);

    // ---- layer 2: h -> d_out (csr_src region is dead by the time GEMM writes) ----
    gather_kernel<<<GB, 256, 0, stream>>>(h, rowptr, csr_src, dinv, agg);
    pack_w_kernel<64><<<64, 256, 0, stream>>>(Wl2, Wr2, wcat);
    gemm_kernel<64, false><<<GM, 256, 0, stream>>>(agg, h, wcat, b2, out, nullptr);
}

// Round 4
// 560.459 us; speedup vs baseline: 14.9954x; 1.4456x over previous
//
#include <hip/hip_runtime.h>

#define NND 50000
#define NED 1600000
#define EPSBN 1e-5f
#define SCAN_B 256
#define NBLK ((NND + SCAN_B - 1) / SCAN_B)   // 196

typedef __attribute__((ext_vector_type(8))) short short8;
typedef __attribute__((ext_vector_type(4))) float f32x4;

__device__ __forceinline__ float bf_lo(unsigned u) {
    union { unsigned u; float f; } c; c.u = u << 16; return c.f;
}
__device__ __forceinline__ float bf_hi(unsigned u) {
    union { unsigned u; float f; } c; c.u = u & 0xffff0000u; return c.f;
}
__device__ __forceinline__ unsigned short f2b(float f) {
    union { float f; unsigned u; } c; c.f = f;
    unsigned r = (c.u + 0x7fffu + ((c.u >> 16) & 1u)) >> 16;
    return (unsigned short)r;
}

// ---------------- degree histogram ----------------
__global__ __launch_bounds__(256) void deg_kernel(const int* __restrict__ dst,
                                                  int* __restrict__ deg) {
    int i = blockIdx.x * 256 + threadIdx.x;
    if (i < NED) atomicAdd(&deg[dst[i]], 1);
}

__global__ __launch_bounds__(256) void deginv_kernel(const int* __restrict__ deg,
                                                     float* __restrict__ dinv) {
    int i = blockIdx.x * 256 + threadIdx.x;
    if (i < NND) dinv[i] = 1.0f / (float)(deg[i] > 1 ? deg[i] : 1);
}

// ---------------- hierarchical exclusive scan: deg -> rowptr ----------------
__global__ __launch_bounds__(SCAN_B) void scan1_kernel(const int* __restrict__ deg,
                                                       int* __restrict__ rowptr,
                                                       int* __restrict__ bsum) {
    __shared__ int s[SCAN_B];
    int t = threadIdx.x;
    int i = blockIdx.x * SCAN_B + t;
    int v = (i < NND) ? deg[i] : 0;
    s[t] = v;
    __syncthreads();
#pragma unroll
    for (int o = 1; o < SCAN_B; o <<= 1) {
        int add = (t >= o) ? s[t - o] : 0;
        __syncthreads();
        s[t] += add;
        __syncthreads();
    }
    if (i < NND) rowptr[i] = s[t] - v;
    if (t == SCAN_B - 1) bsum[blockIdx.x] = s[t];
}

__global__ __launch_bounds__(SCAN_B) void scan2_kernel(int* __restrict__ bsum,
                                                       int* __restrict__ boff) {
    __shared__ int s[SCAN_B];
    int t = threadIdx.x;
    int v = (t < NBLK) ? bsum[t] : 0;
    s[t] = v;
    __syncthreads();
#pragma unroll
    for (int o = 1; o < SCAN_B; o <<= 1) {
        int add = (t >= o) ? s[t - o] : 0;
        __syncthreads();
        s[t] += add;
        __syncthreads();
    }
    if (t < NBLK) boff[t] = s[t] - v;
}

__global__ __launch_bounds__(SCAN_B) void scan3_kernel(int* __restrict__ rowptr,
                                                       const int* __restrict__ boff) {
    int i = blockIdx.x * SCAN_B + threadIdx.x;
    if (i < NND) rowptr[i] += boff[blockIdx.x];
    if (i == 0) rowptr[NND] = NED;
}

// ---------------- CSR fill ----------------
__global__ __launch_bounds__(256) void csr_fill_kernel(const int* __restrict__ src,
                                                       const int* __restrict__ dst,
                                                       const int* __restrict__ rowptr,
                                                       int* __restrict__ cnt,
                                                       int* __restrict__ csr_src) {
    int e = blockIdx.x * 256 + threadIdx.x;
    if (e >= NED) return;
    int d = dst[e];
    int pos = rowptr[d] + atomicAdd(&cnt[d], 1);
    csr_src[pos] = src[e];
}

// ---------------- fp32 -> bf16 cast (8 elems/thread) ----------------
__global__ __launch_bounds__(256) void cast_bf16_kernel(const float* __restrict__ x,
                                                        unsigned short* __restrict__ xb) {
    int i = blockIdx.x * 256 + threadIdx.x;
    if (i >= NND * 16) return;
    const float4* p = (const float4*)x + (size_t)i * 2;
    float4 a = p[0], b = p[1];
    uint4 o;
    o.x = f2b(a.x) | ((unsigned)f2b(a.y) << 16);
    o.y = f2b(a.z) | ((unsigned)f2b(a.w) << 16);
    o.z = f2b(b.x) | ((unsigned)f2b(b.y) << 16);
    o.w = f2b(b.z) | ((unsigned)f2b(b.w) << 16);
    ((uint4*)xb)[i] = o;
}

// ---------------- gather-mean (bf16 payload, fp32 accum): 1 wave/node ----------------
// quarter-wave: 4 neighbors/iter, each 16-lane group reads a 256B bf16 row (16B/lane)
__global__ __launch_bounds__(256) void gather_kernel(const unsigned short* __restrict__ xb,
                                                     const int* __restrict__ rowptr,
                                                     const int* __restrict__ csr_src,
                                                     const float* __restrict__ dinv,
                                                     unsigned short* __restrict__ aggb) {
    int w = threadIdx.x >> 6;
    int node = blockIdx.x * 4 + w;
    if (node >= NND) return;
    int lane = threadIdx.x & 63;
    int q = lane >> 4;        // neighbor slot 0..3
    int c8 = lane & 15;       // 8-channel chunk
    int beg = rowptr[node], end = rowptr[node + 1];
    const uint4* xv = (const uint4*)xb;

    float acc[8];
#pragma unroll
    for (int i = 0; i < 8; ++i) acc[i] = 0.f;

    for (int j = beg + q; j < end; j += 4) {
        int s = csr_src[j];
        uint4 v = xv[(size_t)s * 16 + c8];
        acc[0] += bf_lo(v.x); acc[1] += bf_hi(v.x);
        acc[2] += bf_lo(v.y); acc[3] += bf_hi(v.y);
        acc[4] += bf_lo(v.z); acc[5] += bf_hi(v.z);
        acc[6] += bf_lo(v.w); acc[7] += bf_hi(v.w);
    }
#pragma unroll
    for (int i = 0; i < 8; ++i) {
        acc[i] += __shfl_xor(acc[i], 16);
        acc[i] += __shfl_xor(acc[i], 32);
    }
    if (q == 0) {
        float dv = dinv[node];
        uint4 o;
        o.x = f2b(acc[0] * dv) | ((unsigned)f2b(acc[1] * dv) << 16);
        o.y = f2b(acc[2] * dv) | ((unsigned)f2b(acc[3] * dv) << 16);
        o.z = f2b(acc[4] * dv) | ((unsigned)f2b(acc[5] * dv) << 16);
        o.w = f2b(acc[6] * dv) | ((unsigned)f2b(acc[7] * dv) << 16);
        ((uint4*)aggb)[(size_t)node * 16 + c8] = o;
    }
}

// ---------------- pack W into MFMA-fragment-major bf16 ----------------
// wpack[t = (ks*NCF+cf)*64 + l][j] = W[c = cf*16+(l&15)][k = ks*32+(l>>4)*8+j]
template<int NCF>
__global__ __launch_bounds__(256) void pack_w_kernel(const float* __restrict__ Wl,
                                                     const float* __restrict__ Wr,
                                                     unsigned short* __restrict__ wpack) {
    int t = blockIdx.x * 256 + threadIdx.x;
    if (t >= 8 * NCF * 64) return;
    int rem = t % (NCF * 64);
    int ks = t / (NCF * 64);
    int cf = rem >> 6, l = rem & 63;
    int c = cf * 16 + (l & 15);
    int kbase = ks * 32 + ((l >> 4) * 8);
    unsigned short v[8];
#pragma unroll
    for (int j = 0; j < 8; ++j) {
        int k = kbase + j;
        float w = (k < 128) ? Wl[c * 128 + k] : Wr[c * 128 + (k - 128)];
        v[j] = f2b(w);
    }
    uint4 o;
    o.x = v[0] | ((unsigned)v[1] << 16);
    o.y = v[2] | ((unsigned)v[3] << 16);
    o.z = v[4] | ((unsigned)v[5] << 16);
    o.w = v[6] | ((unsigned)v[7] << 16);
    ((uint4*)wpack)[t] = o;
}

// ---------------- MFMA dual GEMM: out = [aggb | xinb] @ Wcat^T (+bias) ----------------
// 4 waves/block, 64 rows/block, NCOL = NCF*16 cols. bf16 in, fp32 acc.
// DO_STATS: out bf16, BN stats epilogue, no bias (BN absorbs it).
// !DO_STATS: out fp32 + bias. out may alias xinb (block reads only its own rows
// before the syncthreads; stores after).
template<int NCF, bool DO_STATS>
__global__ __launch_bounds__(256) void gemm_mfma_kernel(const unsigned short* __restrict__ aggb,
                                                        const unsigned short* xinb,
                                                        const unsigned short* __restrict__ wpack,
                                                        const float* __restrict__ bias,
                                                        void* outv,
                                                        float* __restrict__ stats) {
    constexpr int NCOL = NCF * 16;
    __shared__ float o_s[64][NCOL + 4];
    __shared__ float sum_s[DO_STATS ? 4 : 1][DO_STATS ? 128 : 1];
    __shared__ float sq_s[DO_STATS ? 4 : 1][DO_STATS ? 128 : 1];

    const int t = threadIdx.x, wave = t >> 6, lane = t & 63;
    const int row0 = blockIdx.x * 64;
    const int arow = row0 + wave * 16 + (lane & 15);
    const bool avalid = arow < NND;
    const int ko = (lane >> 4) * 8;

    f32x4 acc[NCF];
#pragma unroll
    for (int cf = 0; cf < NCF; ++cf) acc[cf] = (f32x4){0.f, 0.f, 0.f, 0.f};

    const short8* wp = (const short8*)wpack;
#pragma unroll
    for (int ks = 0; ks < 8; ++ks) {
        short8 a = {0, 0, 0, 0, 0, 0, 0, 0};
        if (avalid) {
            int k = ks * 32 + ko;
            const unsigned short* base = (k < 128)
                ? (aggb + (size_t)arow * 128 + k)
                : (xinb + (size_t)arow * 128 + (k - 128));
            a = *(const short8*)base;
        }
#pragma unroll
        for (int cf = 0; cf < NCF; ++cf) {
            short8 b = wp[(ks * NCF + cf) * 64 + lane];
            acc[cf] = __builtin_amdgcn_mfma_f32_16x16x32_bf16(a, b, acc[cf], 0, 0, 0);
        }
    }

    // stage C tile (pre-BN, no bias for stats layers) into LDS for coalesced stores
#pragma unroll
    for (int cf = 0; cf < NCF; ++cf)
#pragma unroll
        for (int r = 0; r < 4; ++r)
            o_s[wave * 16 + (lane >> 4) * 4 + r][cf * 16 + (lane & 15)] = acc[cf][r];

    if (DO_STATS) {
        // invalid rows contribute exact 0 to both sums (A rows zeroed, no bias)
#pragma unroll
        for (int cf = 0; cf < NCF; ++cf) {
            float s = acc[cf][0] + acc[cf][1] + acc[cf][2] + acc[cf][3];
            float q = acc[cf][0] * acc[cf][0] + acc[cf][1] * acc[cf][1]
                    + acc[cf][2] * acc[cf][2] + acc[cf][3] * acc[cf][3];
            s += __shfl_xor(s, 16); s += __shfl_xor(s, 32);
            q += __shfl_xor(q, 16); q += __shfl_xor(q, 32);
            if (lane < 16) {
                sum_s[wave][cf * 16 + lane] = s;
                sq_s[wave][cf * 16 + lane] = q;
            }
        }
    }
    __syncthreads();

    // pass 2: coalesced stores (+bias for non-stats layer)
    const int r = t >> 2;
    const int grow = row0 + r;
    const int c0 = (t & 3) * (NCOL / 4);
    if (grow < NND) {
        if (DO_STATS) {
            unsigned short* out = (unsigned short*)outv;
#pragma unroll
            for (int g = 0; g < NCOL / 32; ++g) {   // 8 bf16 per uint4
                float v0 = o_s[r][c0 + g * 8 + 0], v1 = o_s[r][c0 + g * 8 + 1];
                float v2 = o_s[r][c0 + g * 8 + 2], v3 = o_s[r][c0 + g * 8 + 3];
                float v4 = o_s[r][c0 + g * 8 + 4], v5 = o_s[r][c0 + g * 8 + 5];
                float v6 = o_s[r][c0 + g * 8 + 6], v7 = o_s[r][c0 + g * 8 + 7];
                uint4 o;
                o.x = f2b(v0) | ((unsigned)f2b(v1) << 16);
                o.y = f2b(v2) | ((unsigned)f2b(v3) << 16);
                o.z = f2b(v4) | ((unsigned)f2b(v5) << 16);
                o.w = f2b(v6) | ((unsigned)f2b(v7) << 16);
                ((uint4*)(out + (size_t)grow * NCOL + c0))[g] = o;
            }
        } else {
            float* out = (float*)outv;
#pragma unroll
            for (int g = 0; g < NCOL / 16; ++g) {
                float4 o;
                o.x = o_s[r][c0 + g * 4 + 0] + bias[c0 + g * 4 + 0];
                o.y = o_s[r][c0 + g * 4 + 1] + bias[c0 + g * 4 + 1];
                o.z = o_s[r][c0 + g * 4 + 2] + bias[c0 + g * 4 + 2];
                o.w = o_s[r][c0 + g * 4 + 3] + bias[c0 + g * 4 + 3];
                ((float4*)(out + (size_t)grow * NCOL + c0))[g] = o;
            }
        }
    }

    if (DO_STATS && t < 128) {
        float s = sum_s[0][t] + sum_s[1][t] + sum_s[2][t] + sum_s[3][t];
        float q = sq_s[0][t] + sq_s[1][t] + sq_s[2][t] + sq_s[3][t];
        unsafeAtomicAdd(&stats[t], s);
        unsafeAtomicAdd(&stats[128 + t], q);
    }
}

// ---------------- BN finalize ----------------
__global__ void bn_finalize_kernel(const float* __restrict__ stats,
                                   const float* __restrict__ gamma,
                                   const float* __restrict__ beta,
                                   float* __restrict__ ab) {
    int c = threadIdx.x;  // 128
    float mu = stats[c] * (1.0f / NND);
    float var = stats[128 + c] * (1.0f / NND) - mu * mu;
    float rs = rsqrtf(var + EPSBN);
    float a = gamma[c] * rs;
    ab[c] = a;
    ab[128 + c] = beta[c] - mu * a;
}

// ---------------- BN + ReLU in place on bf16 h ----------------
__global__ __launch_bounds__(256) void bn_relu_kernel(unsigned short* __restrict__ h,
                                                      const float* __restrict__ ab) {
    int i = blockIdx.x * 256 + threadIdx.x;
    if (i >= NND * 16) return;
    uint4 v = ((uint4*)h)[i];
    int c0 = (i & 15) * 8;
    float o[8] = {bf_lo(v.x), bf_hi(v.x), bf_lo(v.y), bf_hi(v.y),
                  bf_lo(v.z), bf_hi(v.z), bf_lo(v.w), bf_hi(v.w)};
#pragma unroll
    for (int j = 0; j < 8; ++j)
        o[j] = fmaxf(o[j] * ab[c0 + j] + ab[128 + c0 + j], 0.f);
    uint4 w;
    w.x = f2b(o[0]) | ((unsigned)f2b(o[1]) << 16);
    w.y = f2b(o[2]) | ((unsigned)f2b(o[3]) << 16);
    w.z = f2b(o[4]) | ((unsigned)f2b(o[5]) << 16);
    w.w = f2b(o[6]) | ((unsigned)f2b(o[7]) << 16);
    ((uint4*)h)[i] = w;
}

extern "C" void kernel_launch(void* const* d_in, const int* in_sizes, int n_in,
                              void* d_out, int out_size, void* d_ws, size_t ws_size,
                              hipStream_t stream) {
    const float* x   = (const float*)d_in[0];
    const int*   ei  = (const int*)d_in[1];
    const int* src = ei;
    const int* dst = ei + NED;
    const float* Wl0 = (const float*)d_in[2];
    const float* Wr0 = (const float*)d_in[3];
    const float* g0  = (const float*)d_in[5];
    const float* be0 = (const float*)d_in[6];
    const float* Wl1 = (const float*)d_in[7];
    const float* Wr1 = (const float*)d_in[8];
    const float* g1  = (const float*)d_in[10];
    const float* be1 = (const float*)d_in[11];
    const float* Wl2 = (const float*)d_in[12];
    const float* Wr2 = (const float*)d_in[13];
    const float* b2  = (const float*)d_in[14];
    float* out = (float*)d_out;
    // b0/b1 unused: bias cancels under training-mode BatchNorm (shift invariance).

    // workspace layout (16B-aligned sections):
    // aggb | xb | h  (bf16, NF each) | dinv f32 | deg | rowptr(+pad) | bsum | boff | wpack | stats | ab
    const size_t NF = (size_t)NND * 128;
    unsigned short* aggb = (unsigned short*)d_ws;
    unsigned short* xb   = aggb + NF;
    unsigned short* h    = xb + NF;
    float* dinv   = (float*)(h + NF);
    int*   deg    = (int*)(dinv + NND);
    int*   rowptr = deg + NND;                 // NND+1 used, pad to NND+4
    int*   bsum   = rowptr + NND + 4;          // 200 (padded)
    int*   boff   = bsum + 200;                // 200 (padded)
    unsigned short* wpack = (unsigned short*)(boff + 200);   // 8*8*64*8 = 32768 shorts
    float* stats  = (float*)(wpack + 32768);
    float* ab     = stats + 256;
    int*   csr_src = (int*)d_out;              // 6.4 MB of the 12.8 MB output; dead before L2 GEMM

    const int GB = (NND + 3) / 4;       // gather blocks
    const int GM = (NND + 63) / 64;     // gemm blocks

    // ---- x -> bf16, CSR build ----
    cast_bf16_kernel<<<(NND * 16 + 255) / 256, 256, 0, stream>>>(x, xb);
    hipMemsetAsync(deg, 0, NND * sizeof(int), stream);
    deg_kernel<<<(NED + 255) / 256, 256, 0, stream>>>(dst, deg);
    deginv_kernel<<<(NND + 255) / 256, 256, 0, stream>>>(deg, dinv);
    scan1_kernel<<<NBLK, SCAN_B, 0, stream>>>(deg, rowptr, bsum);
    scan2_kernel<<<1, SCAN_B, 0, stream>>>(bsum, boff);
    scan3_kernel<<<NBLK, SCAN_B, 0, stream>>>(rowptr, boff);
    hipMemsetAsync(deg, 0, NND * sizeof(int), stream);
    csr_fill_kernel<<<(NED + 255) / 256, 256, 0, stream>>>(src, dst, rowptr, deg, csr_src);

    // ---- layer 0: xb -> h ----
    gather_kernel<<<GB, 256, 0, stream>>>(xb, rowptr, csr_src, dinv, aggb);
    pack_w_kernel<8><<<16, 256, 0, stream>>>(Wl0, Wr0, wpack);
    hipMemsetAsync(stats, 0, 256 * sizeof(float), stream);
    gemm_mfma_kernel<8, true><<<GM, 256, 0, stream>>>(aggb, xb, wpack, nullptr, h, stats);
    bn_finalize_kernel<<<1, 128, 0, stream>>>(stats, g0, be0, ab);
    bn_relu_kernel<<<(NND * 16 + 255) / 256, 256, 0, stream>>>(h, ab);

    // ---- layer 1: h -> h (in-place) ----
    gather_kernel<<<GB, 256, 0, stream>>>(h, rowptr, csr_src, dinv, aggb);
    pack_w_kernel<8><<<16, 256, 0, stream>>>(Wl1, Wr1, wpack);
    hipMemsetAsync(stats, 0, 256 * sizeof(float), stream);
    gemm_mfma_kernel<8, true><<<GM, 256, 0, stream>>>(aggb, h, wpack, nullptr, h, stats);
    bn_finalize_kernel<<<1, 128, 0, stream>>>(stats, g1, be1, ab);
    bn_relu_kernel<<<(NND * 16 + 255) / 256, 256, 0, stream>>>(h, ab);

    // ---- layer 2: h -> d_out (fp32, +bias, no BN) ----
    gather_kernel<<<GB, 256, 0, stream>>>(h, rowptr, csr_src, dinv, aggb);
    pack_w_kernel<4><<<8, 256, 0, stream>>>(Wl2, Wr2, wpack);
    gemm_mfma_kernel<4, false><<<GM, 256, 0, stream>>>(aggb, h, wpack, b2, out, nullptr);
}